// Round 23
// baseline (104.214 us; speedup 1.0000x reference)
//
#include <hip/hip_runtime.h>
#include <hip/hip_bf16.h>

typedef __bf16 bf16;
typedef bf16 bf16x8 __attribute__((ext_vector_type(8)));
typedef float f32x4 __attribute__((ext_vector_type(4)));
typedef float f32x16 __attribute__((ext_vector_type(16)));
typedef unsigned int u32;
typedef u32 u32x2 __attribute__((ext_vector_type(2)));
typedef u32 u32x4 __attribute__((ext_vector_type(4)));
typedef int i32x2 __attribute__((ext_vector_type(2)));

// Problem constants
// x: [16][256][64][64] f32; w_qkv: [768][256]; b_qkv: [768]; pos: [1024][32]
// out: [16][256][32][32] f32  (= [b][h*32+d][n], n = hp*32+wp)

__device__ __forceinline__ u32 packbf2(float lo, float hi) {
    unsigned short a = __builtin_bit_cast(unsigned short, (bf16)lo);
    unsigned short b = __builtin_bit_cast(unsigned short, (bf16)hi);
    return (u32)a | ((u32)b << 16);
}

#if __has_builtin(__builtin_amdgcn_exp2f)
#define EXP2(x) __builtin_amdgcn_exp2f(x)
#else
#define EXP2(x) __expf((x)*0.69314718055994531f)
#endif

__device__ __forceinline__ i32x2 pl32swap(u32 a, u32 b) {
#if __has_builtin(__builtin_amdgcn_permlane32_swap)
    return __builtin_amdgcn_permlane32_swap((int)a, (int)b, false, false);
#else
    int lid = __builtin_amdgcn_mbcnt_hi(~0u, __builtin_amdgcn_mbcnt_lo(~0u, 0));
    u32 ax = (u32)__shfl_xor((int)a, 32);
    u32 bx = (u32)__shfl_xor((int)b, 32);
    i32x2 r;
    r.x = (int)(lid < 32 ? a : bx);
    r.y = (int)(lid < 32 ? ax : b);
    return r;
#endif
}

__device__ __forceinline__ f32x16 zero16() {
    f32x16 z;
#pragma unroll
    for (int i = 0; i < 16; ++i) z[i] = 0.f;
    return z;
}

// async global->LDS, 16B per lane; ldst must be the wave-uniform base
__device__ __forceinline__ void gload_lds16(const bf16* gsrc, bf16* ldst) {
    __builtin_amdgcn_global_load_lds(
        (const __attribute__((address_space(1))) void*)gsrc,
        (__attribute__((address_space(3))) void*)ldst, 16, 0, 0);
}

// pin memory-op program order at IR level and scheduler level
#define MEMFENCE()                               \
    do {                                         \
        asm volatile("" ::: "memory");           \
        __builtin_amdgcn_sched_barrier(0);       \
    } while (0)

#define WAITV(N)                                                   \
    do {                                                           \
        asm volatile("s_waitcnt vmcnt(" #N ")" ::: "memory");      \
        __builtin_amdgcn_sched_barrier(0);                         \
    } while (0)

#define WAITLGKM()                                                 \
    do {                                                           \
        asm volatile("s_waitcnt lgkmcnt(0)" ::: "memory");         \
        __builtin_amdgcn_sched_barrier(0);                         \
    } while (0)

// ---------------------------------------------------------------------------
// K2: w f32 [768][256] -> bf16 same layout
__global__ __launch_bounds__(256) void k_convert_w(const float* __restrict__ w,
                                                   bf16* __restrict__ wb) {
    int i = (blockIdx.x * 256 + threadIdx.x) * 8;
    float4 a = *reinterpret_cast<const float4*>(w + i);
    float4 b4 = *reinterpret_cast<const float4*>(w + i + 4);
    bf16x8 o;
    o[0] = (bf16)a.x;  o[1] = (bf16)a.y;  o[2] = (bf16)a.z;  o[3] = (bf16)a.w;
    o[4] = (bf16)b4.x; o[5] = (bf16)b4.y; o[6] = (bf16)b4.z; o[7] = (bf16)b4.w;
    *reinterpret_cast<bf16x8*>(wb + i) = o;
}

// ---------------------------------------------------------------------------
// K3: GEMM + pool + fused Q/K/V out + fused transpose staging.
//     64-pixel tiles (r18 geometry WITHOUT the fatal VGPR cap): acc[2][4],
//     LDS 32 KB -> expect ~150-170 VGPR naturally -> 3 waves/SIMD and more
//     co-resident blocks (block-level overlap per r9 ablation). Tile =
//     rows {2rr, 2rr+1} x 32 cols (pixels base0 + rowsel*64 + pl).
//     Slot map: s = (pl>>1) | ((pl&1)<<4) | (rowsel<<5); pool-mates of
//     output (q) are slots {fc*16+q, fc=0..3} at the SAME lane.
//     Staging: c-pairs, packbf2 + ds_write_b32 (key=(s&7)<<3, bits>=3).
//     NEVER cap VGPR (r18: cap -> spill catastrophe).
__global__ __launch_bounds__(256) void k_gemm_pool(const float* __restrict__ x,
                                                   const bf16* __restrict__ wb,
                                                   const float* __restrict__ bias,
                                                   const float* __restrict__ pos,
                                                   bf16* __restrict__ Qb,
                                                   bf16* __restrict__ Kb,
                                                   bf16* __restrict__ Vb) {
    __shared__ __align__(16) bf16 bt[64 * 256];    // 32 KB X-tile [slot][c]
    int b = blockIdx.y, nt = blockIdx.x;           // nt 0..63
    int rr = nt >> 1, hh2 = nt & 1;                // row-pair, half-row
    int base0 = rr * 128 + hh2 * 32;               // pixel base
    int t = threadIdx.x;
    int w = t >> 6, lane = t & 63, g = lane >> 4, q = lane & 15;

    const float* xp = x + (size_t)b * 256 * 4096;  // + c*4096 + p
    const bf16* wb_w = wb + (size_t)(w * 32) * 256;

    // ---- fused transpose staging: 64 local pixels x 256 c ----
    {
        int j0 = (t & 15) * 4;         // local pixel quad 0,4,..,60
        int cg = (t >> 4) * 2;         // c-pair base 0,2,..,30; pass adds 32
        int rowsel = j0 >> 5;
        int pofs = base0 + rowsel * 64 + (j0 & 31);
        int sd[4], key[4];
#pragma unroll
        for (int i = 0; i < 4; ++i) {
            int pl = (j0 + i) & 31;
            int s = (pl >> 1) | ((pl & 1) << 4) | (rowsel << 5);
            sd[i] = s * 256;
            key[i] = (s & 7) << 3;
        }
        u32* btw = reinterpret_cast<u32*>(bt);
#pragma unroll
        for (int pass = 0; pass < 8; ++pass) {
            int c = cg + pass * 32;
            float4 v0 = *reinterpret_cast<const float4*>(xp + (size_t)c * 4096 + pofs);
            float4 v1 = *reinterpret_cast<const float4*>(xp + (size_t)(c + 1) * 4096 + pofs);
            btw[(sd[0] + (c ^ key[0])) >> 1] = packbf2(v0.x, v1.x);
            btw[(sd[1] + (c ^ key[1])) >> 1] = packbf2(v0.y, v1.y);
            btw[(sd[2] + (c ^ key[2])) >> 1] = packbf2(v0.z, v1.z);
            btw[(sd[3] + (c ^ key[3])) >> 1] = packbf2(v0.w, v1.w);
        }
    }

    bf16x8 Ac[4], An[4];
#define LOADA(MT, KC, DST)                                                     \
    {                                                                          \
        _Pragma("unroll")                                                      \
        for (int ks = 0; ks < 2; ++ks)                                         \
            _Pragma("unroll")                                                  \
            for (int fr = 0; fr < 2; ++fr)                                     \
                DST[ks * 2 + fr] = *reinterpret_cast<const bf16x8*>(           \
                    wb_w + (size_t)((MT) * 128 + fr * 16 + q) * 256 +          \
                    (KC) * 64 + ks * 32 + g * 8);                              \
    }
    LOADA(0, 0, Ac);
    MEMFENCE();

    // staging is ds_write-tracked (lgkm); drain it, then block barrier
    WAITLGKM();
    __builtin_amdgcn_s_barrier();
    __builtin_amdgcn_sched_barrier(0);

    const float QSCALE = 0.2550406682649681f;  // log2(e)/sqrt(32)
    int n_g = rr * 32 + hh2 * 16 + q;          // output n for this lane

    for (int mt = 0; mt < 6; ++mt) {
        f32x4 acc[2][4];
#pragma unroll
        for (int fr = 0; fr < 2; ++fr)
#pragma unroll
            for (int fc = 0; fc < 4; ++fc) acc[fr][fc] = (f32x4){0.f, 0.f, 0.f, 0.f};

        // ---- 64 MFMAs (4 kc x 2 ks x 4 fc x 2 fr), bt read-only ----
#pragma unroll
        for (int kc = 0; kc < 4; ++kc) {
            if (kc < 3) {
                LOADA(mt, kc + 1, An);
            } else if (mt < 5) {
                LOADA(mt + 1, 0, An);
            }
#pragma unroll
            for (int ks = 0; ks < 2; ++ks) {
#pragma unroll
                for (int fc = 0; fc < 4; ++fc) {
                    int co = kc * 64 + (((ks * 4 + g) ^ (q & 7)) << 3);
                    bf16x8 bfv = *reinterpret_cast<const bf16x8*>(
                        &bt[(fc * 16 + q) * 256 + co]);
                    acc[0][fc] = __builtin_amdgcn_mfma_f32_16x16x32_bf16(
                        Ac[ks * 2 + 0], bfv, acc[0][fc], 0, 0, 0);
                    acc[1][fc] = __builtin_amdgcn_mfma_f32_16x16x32_bf16(
                        Ac[ks * 2 + 1], bfv, acc[1][fc], 0, 0, 0);
                }
            }
#pragma unroll
            for (int i = 0; i < 4; ++i) Ac[i] = An[i];
        }

        // ---- in-register epilogue: pool over fc axis (4 pool-mates) ----
        int m0 = mt * 128;
        int sec = mt >> 1;                      // 0=Q, 1=K, 2=V
        int hh = ((m0 >> 5) + w) & 7;           // head
        size_t bh = (size_t)(b * 8 + hh) * 32768;
#pragma unroll
        for (int fr = 0; fr < 2; ++fr) {
            int dbase = fr * 16 + g * 4;        // d for r=0..3
            float4 bs = *reinterpret_cast<const float4*>(&bias[m0 + w * 32 + dbase]);
            float vm[4];
#pragma unroll
            for (int r = 0; r < 4; ++r) {
                float a0 = fmaxf(acc[fr][0][r], acc[fr][1][r]);
                float a1 = fmaxf(acc[fr][2][r], acc[fr][3][r]);
                vm[r] = fmaxf(a0, a1) + ((const float*)&bs)[r];
            }
            if (sec == 0) {
                float4 pv = *reinterpret_cast<const float4*>(
                    &pos[(size_t)n_g * 32 + dbase]);
                u32x2 o2 = {packbf2((vm[0] + pv.x) * QSCALE, (vm[1] + pv.y) * QSCALE),
                            packbf2((vm[2] + pv.z) * QSCALE, (vm[3] + pv.w) * QSCALE)};
                *reinterpret_cast<u32x2*>(Qb + bh + (size_t)n_g * 32 + dbase) = o2;
            } else if (sec == 1) {
                u32x2 o2 = {packbf2(vm[0], vm[1]), packbf2(vm[2], vm[3])};
                *reinterpret_cast<u32x2*>(Kb + bh + (size_t)n_g * 32 + dbase) = o2;
            } else {
#pragma unroll
                for (int r = 0; r < 4; ++r)
                    Vb[bh + (size_t)(dbase + r) * 1024 + n_g] = (bf16)vm[r];
            }
        }
    }
#undef LOADA
}

// ---------------------------------------------------------------------------
// K5: attention — EXACT r16 production structure (verified ~31us, VGPR 52).
// 4 waves, 64-key tiles, 16 iters (1024 keys), dbuf LDS staging, WAITV(2)
// steady / (0) last, restage gated tt<14.
#define SUBTILE_FULL(K0, K1, V0, V1)                                           \
    {                                                                          \
        f32x16 s = __builtin_amdgcn_mfma_f32_32x32x16_bf16(K0, qf0, zero16(), 0, 0, 0); \
        s = __builtin_amdgcn_mfma_f32_32x32x16_bf16(K1, qf1, s, 0, 0, 0);      \
        float p[16];                                                           \
        _Pragma("unroll")                                                      \
        for (int r = 0; r < 16; ++r) p[r] = EXP2(s[r]);                        \
        float ts = (((p[0]+p[1])+(p[2]+p[3]))+((p[4]+p[5])+(p[6]+p[7]))) +     \
                   (((p[8]+p[9])+(p[10]+p[11]))+((p[12]+p[13])+(p[14]+p[15])));\
        run_s += ts;                                                           \
        u32 pk0 = packbf2(p[0],p[1]),   pk1 = packbf2(p[2],p[3]);              \
        u32 pk2 = packbf2(p[4],p[5]),   pk3 = packbf2(p[6],p[7]);              \
        u32 pk4 = packbf2(p[8],p[9]),   pk5 = packbf2(p[10],p[11]);            \
        u32 pk6 = packbf2(p[12],p[13]), pk7 = packbf2(p[14],p[15]);            \
        i32x2 r02 = pl32swap(pk0, pk2); i32x2 r13 = pl32swap(pk1, pk3);        \
        i32x2 r46 = pl32swap(pk4, pk6); i32x2 r57 = pl32swap(pk5, pk7);        \
        u32x4 b0v = {(u32)r02.x, (u32)r13.x, (u32)r02.y, (u32)r13.y};          \
        u32x4 b1v = {(u32)r46.x, (u32)r57.x, (u32)r46.y, (u32)r57.y};          \
        bf16x8 pb0 = __builtin_bit_cast(bf16x8, b0v);                          \
        bf16x8 pb1 = __builtin_bit_cast(bf16x8, b1v);                          \
        o = __builtin_amdgcn_mfma_f32_32x32x16_bf16(V0, pb0, o, 0, 0, 0);      \
        o = __builtin_amdgcn_mfma_f32_32x32x16_bf16(V1, pb1, o, 0, 0, 0);      \
    }

__global__ __launch_bounds__(256) void k_attn(const bf16* __restrict__ Q,
                                              const bf16* __restrict__ K,
                                              const bf16* __restrict__ V,
                                              float* __restrict__ out) {
    __shared__ __align__(16) bf16 kt[2][2048];
    __shared__ __align__(16) bf16 vt[2][2048];
    int h = blockIdx.x, b = blockIdx.y, qb = blockIdx.z;
    int t = threadIdx.x, w = t >> 6, lane = t & 63;
    int lq = lane & 31, hi = lane >> 5, hi8 = hi * 8;
    size_t bh = (size_t)b * 8 + h;
    const bf16* Qp = Q + bh * 32768;
    const bf16* Kp = K + bh * 32768;
    const bf16* Vp = V + bh * 32768;
    float* Op = out + ((size_t)(b * 256 + h * 32)) * 1024;
    int q0 = qb * 128 + w * 32;

    bf16x8 qf0 = *reinterpret_cast<const bf16x8*>(Qp + (size_t)(q0 + lq) * 32 + hi8);
    bf16x8 qf1 = *reinterpret_cast<const bf16x8*>(Qp + (size_t)(q0 + lq) * 32 + 16 + hi8);

    int srow = lane & 31;
    int sh = w & 1, isV = w >> 1;
    const bf16* sg0;
    if (!isV) sg0 = Kp + (size_t)(sh * 32 + srow) * 32 + (lane >> 5) * 8;
    else      sg0 = Vp + (size_t)srow * 1024 + sh * 32 + (lane >> 5) * 8;
    const bf16* sg1 = sg0 + 16;
    int d0 = sh * 1024, d1 = sh * 1024 + 512;

#define STAGE64(BB, TT)                                                        \
    do {                                                                       \
        if (!isV) {                                                            \
            gload_lds16(sg0 + (size_t)(TT) * 2048, &kt[BB][d0]);               \
            gload_lds16(sg1 + (size_t)(TT) * 2048, &kt[BB][d1]);               \
        } else {                                                               \
            gload_lds16(sg0 + (TT) * 64, &vt[BB][d0]);                         \
            gload_lds16(sg1 + (TT) * 64, &vt[BB][d1]);                         \
        }                                                                      \
    } while (0)

    f32x16 o = zero16();
    float run_s = 0.f;

    STAGE64(0, 0);
    MEMFENCE();
    STAGE64(1, 1);
    MEMFENCE();

    for (int tt = 0; tt < 16; ++tt) {
        int cur = tt & 1;
        if (tt < 15) { WAITV(2); } else { WAITV(0); }
        __builtin_amdgcn_s_barrier();
        __builtin_amdgcn_sched_barrier(0);

        bf16x8 ka0 = *reinterpret_cast<const bf16x8*>(&kt[cur][hi * 256 + lq * 8]);
        bf16x8 ka1 = *reinterpret_cast<const bf16x8*>(&kt[cur][512 + hi * 256 + lq * 8]);
        bf16x8 va0 = *reinterpret_cast<const bf16x8*>(&vt[cur][hi * 256 + lq * 8]);
        bf16x8 va1 = *reinterpret_cast<const bf16x8*>(&vt[cur][512 + hi * 256 + lq * 8]);
        bf16x8 kb0 = *reinterpret_cast<const bf16x8*>(&kt[cur][1024 + hi * 256 + lq * 8]);
        bf16x8 kb1 = *reinterpret_cast<const bf16x8*>(&kt[cur][1536 + hi * 256 + lq * 8]);
        bf16x8 vb0 = *reinterpret_cast<const bf16x8*>(&vt[cur][1024 + hi * 256 + lq * 8]);
        bf16x8 vb1 = *reinterpret_cast<const bf16x8*>(&vt[cur][1536 + hi * 256 + lq * 8]);
        WAITLGKM();
        __builtin_amdgcn_s_barrier();
        __builtin_amdgcn_sched_barrier(0);
        if (tt < 14) STAGE64(cur, tt + 2);
        MEMFENCE();

        SUBTILE_FULL(ka0, ka1, va0, va1);
        SUBTILE_FULL(kb0, kb1, vb0, vb1);
    }
#undef STAGE64

    i32x2 rs = pl32swap(__builtin_bit_cast(u32, run_s), __builtin_bit_cast(u32, run_s));
    float tot = __builtin_bit_cast(float, (u32)rs.x) + __builtin_bit_cast(float, (u32)rs.y);
    float inv = 1.0f / tot;

#pragma unroll
    for (int r = 0; r < 16; ++r) {
        int dd = (r & 3) + 8 * (r >> 2) + 4 * hi;
        Op[(size_t)dd * 1024 + q0 + lq] = o[r] * inv;
    }
}

// ---------------------------------------------------------------------------
extern "C" void kernel_launch(void* const* d_in, const int* in_sizes, int n_in,
                              void* d_out, int out_size, void* d_ws, size_t ws_size,
                              hipStream_t stream) {
    const float* x = (const float*)d_in[0];
    const float* w = (const float*)d_in[1];
    const float* bias = (const float*)d_in[2];
    const float* pos = (const float*)d_in[3];
    float* outp = (float*)d_out;

    char* ws = (char*)d_ws;
    bf16* wb = (bf16*)(ws);               //    393,216
    bf16* Qb = (bf16*)(ws + 393216);      //  8,388,608
    bf16* Kb = (bf16*)(ws + 8781824);     //  8,388,608
    bf16* Vb = (bf16*)(ws + 17170432);    //  8,388,608

    k_convert_w<<<dim3(96), 256, 0, stream>>>(w, wb);
    k_gemm_pool<<<dim3(64, 16), 256, 0, stream>>>(x, wb, bias, pos, Qb, Kb, Vb);
    k_attn<<<dim3(8, 16, 8), 256, 0, stream>>>(Qb, Kb, Vb, outp);
}

// Round 24
// 91.004 us; speedup vs baseline: 1.1452x; 1.1452x over previous
//
#include <hip/hip_runtime.h>
#include <hip/hip_bf16.h>

typedef __bf16 bf16;
typedef bf16 bf16x8 __attribute__((ext_vector_type(8)));
typedef float f32x4 __attribute__((ext_vector_type(4)));
typedef float f32x16 __attribute__((ext_vector_type(16)));
typedef unsigned int u32;
typedef u32 u32x2 __attribute__((ext_vector_type(2)));
typedef u32 u32x4 __attribute__((ext_vector_type(4)));
typedef int i32x2 __attribute__((ext_vector_type(2)));

// Problem constants
// x: [16][256][64][64] f32; w_qkv: [768][256]; b_qkv: [768]; pos: [1024][32]
// out: [16][256][32][32] f32  (= [b][h*32+d][n], n = hp*32+wp)

__device__ __forceinline__ u32 packbf2(float lo, float hi) {
    unsigned short a = __builtin_bit_cast(unsigned short, (bf16)lo);
    unsigned short b = __builtin_bit_cast(unsigned short, (bf16)hi);
    return (u32)a | ((u32)b << 16);
}

#if __has_builtin(__builtin_amdgcn_exp2f)
#define EXP2(x) __builtin_amdgcn_exp2f(x)
#else
#define EXP2(x) __expf((x)*0.69314718055994531f)
#endif

__device__ __forceinline__ i32x2 pl32swap(u32 a, u32 b) {
#if __has_builtin(__builtin_amdgcn_permlane32_swap)
    return __builtin_amdgcn_permlane32_swap((int)a, (int)b, false, false);
#else
    int lid = __builtin_amdgcn_mbcnt_hi(~0u, __builtin_amdgcn_mbcnt_lo(~0u, 0));
    u32 ax = (u32)__shfl_xor((int)a, 32);
    u32 bx = (u32)__shfl_xor((int)b, 32);
    i32x2 r;
    r.x = (int)(lid < 32 ? a : bx);
    r.y = (int)(lid < 32 ? ax : b);
    return r;
#endif
}

__device__ __forceinline__ f32x16 zero16() {
    f32x16 z;
#pragma unroll
    for (int i = 0; i < 16; ++i) z[i] = 0.f;
    return z;
}

// async global->LDS, 16B per lane; ldst must be the wave-uniform base
__device__ __forceinline__ void gload_lds16(const bf16* gsrc, bf16* ldst) {
    __builtin_amdgcn_global_load_lds(
        (const __attribute__((address_space(1))) void*)gsrc,
        (__attribute__((address_space(3))) void*)ldst, 16, 0, 0);
}

// pin memory-op program order at IR level and scheduler level
#define MEMFENCE()                               \
    do {                                         \
        asm volatile("" ::: "memory");           \
        __builtin_amdgcn_sched_barrier(0);       \
    } while (0)

#define WAITV(N)                                                   \
    do {                                                           \
        asm volatile("s_waitcnt vmcnt(" #N ")" ::: "memory");      \
        __builtin_amdgcn_sched_barrier(0);                         \
    } while (0)

#define WAITLGKM()                                                 \
    do {                                                           \
        asm volatile("s_waitcnt lgkmcnt(0)" ::: "memory");         \
        __builtin_amdgcn_sched_barrier(0);                         \
    } while (0)

// ---------------------------------------------------------------------------
// K2: w f32 [768][256] -> bf16 same layout
__global__ __launch_bounds__(256) void k_convert_w(const float* __restrict__ w,
                                                   bf16* __restrict__ wb) {
    int i = (blockIdx.x * 256 + threadIdx.x) * 8;
    float4 a = *reinterpret_cast<const float4*>(w + i);
    float4 b4 = *reinterpret_cast<const float4*>(w + i + 4);
    bf16x8 o;
    o[0] = (bf16)a.x;  o[1] = (bf16)a.y;  o[2] = (bf16)a.z;  o[3] = (bf16)a.w;
    o[4] = (bf16)b4.x; o[5] = (bf16)b4.y; o[6] = (bf16)b4.z; o[7] = (bf16)b4.w;
    *reinterpret_cast<bf16x8*>(wb + i) = o;
}

// ---------------------------------------------------------------------------
// K3: GEMM + pool + fused Q/K/V out, zero-shuffle epilogue + FUSED TRANSPOSE
//     staging (r21/r22 WIN: 128-slot tile, c-pair packbf2 + ds_write_b32).
//     r24: staging pass loop unroll LIMITED to 4 — the full 16-way unroll
//     kept ~32 float4 loads in flight (~128 VGPR) inflating the kernel to
//     212 VGPR -> 2 waves/SIMD. Bounding in-flight loads to 8 float4 should
//     drop VGPR to ~160 -> 3 waves/SIMD (the binding cap per r20 analysis).
//     Slot inverse: s = ((j&31)>>1)|((j&1)<<4)|(bit5(j)<<6)|(bit6(j)<<5).
//     NEVER hard-cap VGPR via launch_bounds (r18 spill catastrophe).
__global__ __launch_bounds__(256) void k_gemm_pool(const float* __restrict__ x,
                                                   const bf16* __restrict__ wb,
                                                   const float* __restrict__ bias,
                                                   const float* __restrict__ pos,
                                                   bf16* __restrict__ Qb,
                                                   bf16* __restrict__ Kb,
                                                   bf16* __restrict__ Vb) {
    __shared__ __align__(16) bf16 bt[128 * 256];   // 64 KB X-tile [slot][c]
    int b = blockIdx.y, nt = blockIdx.x;
    int t = threadIdx.x;
    int w = t >> 6, lane = t & 63, g = lane >> 4, q = lane & 15;

    const float* xp = x + (size_t)b * 256 * 4096 + nt * 128;  // + c*4096 + j
    const bf16* wb_w = wb + (size_t)(w * 32) * 256;

    // ---- fused transpose staging: c-pairs, packed b32 writes ----
    {
        int j0 = (t & 31) * 4;         // pixel quad within tile
        int cg = (t >> 5) * 2;         // c-pair base 0,2,..,14; pass adds 16
        int sd[4];                     // dword base + key info per pixel
        int key[4];
#pragma unroll
        for (int i = 0; i < 4; ++i) {
            int j = j0 + i;
            int s = ((j & 31) >> 1) | ((j & 1) << 4) |
                    (((j >> 5) & 1) << 6) | (((j >> 6) & 1) << 5);
            sd[i] = s * 256;
            key[i] = (s & 7) << 3;
        }
        u32* btw = reinterpret_cast<u32*>(bt);
#pragma unroll 4
        for (int pass = 0; pass < 16; ++pass) {
            int c = cg + pass * 16;
            float4 v0 = *reinterpret_cast<const float4*>(xp + (size_t)c * 4096 + j0);
            float4 v1 = *reinterpret_cast<const float4*>(xp + (size_t)(c + 1) * 4096 + j0);
            btw[(sd[0] + (c ^ key[0])) >> 1] = packbf2(v0.x, v1.x);
            btw[(sd[1] + (c ^ key[1])) >> 1] = packbf2(v0.y, v1.y);
            btw[(sd[2] + (c ^ key[2])) >> 1] = packbf2(v0.z, v1.z);
            btw[(sd[3] + (c ^ key[3])) >> 1] = packbf2(v0.w, v1.w);
        }
    }

    bf16x8 Ac[4], An[4];
#define LOADA(MT, KC, DST)                                                     \
    {                                                                          \
        _Pragma("unroll")                                                      \
        for (int ks = 0; ks < 2; ++ks)                                         \
            _Pragma("unroll")                                                  \
            for (int fr = 0; fr < 2; ++fr)                                     \
                DST[ks * 2 + fr] = *reinterpret_cast<const bf16x8*>(           \
                    wb_w + (size_t)((MT) * 128 + fr * 16 + q) * 256 +          \
                    (KC) * 64 + ks * 32 + g * 8);                              \
    }
    LOADA(0, 0, Ac);
    MEMFENCE();

    // staging is ds_write-tracked (lgkm); drain it, then block barrier
    WAITLGKM();
    __builtin_amdgcn_s_barrier();
    __builtin_amdgcn_sched_barrier(0);

    const float QSCALE = 0.2550406682649681f;  // log2(e)/sqrt(32)

    for (int mt = 0; mt < 6; ++mt) {
        f32x4 acc[2][8];
#pragma unroll
        for (int fr = 0; fr < 2; ++fr)
#pragma unroll
            for (int fc = 0; fc < 8; ++fc) acc[fr][fc] = (f32x4){0.f, 0.f, 0.f, 0.f};

#pragma unroll
        for (int kc = 0; kc < 4; ++kc) {
            if (kc < 3) {
                LOADA(mt, kc + 1, An);
            } else if (mt < 5) {
                LOADA(mt + 1, 0, An);
            }
#pragma unroll
            for (int ks = 0; ks < 2; ++ks) {
#pragma unroll
                for (int fc = 0; fc < 8; ++fc) {
                    int co = kc * 64 + (((ks * 4 + g) ^ (q & 7)) << 3);
                    bf16x8 bfv = *reinterpret_cast<const bf16x8*>(
                        &bt[(fc * 16 + q) * 256 + co]);
                    acc[0][fc] = __builtin_amdgcn_mfma_f32_16x16x32_bf16(
                        Ac[ks * 2 + 0], bfv, acc[0][fc], 0, 0, 0);
                    acc[1][fc] = __builtin_amdgcn_mfma_f32_16x16x32_bf16(
                        Ac[ks * 2 + 1], bfv, acc[1][fc], 0, 0, 0);
                }
            }
#pragma unroll
            for (int i = 0; i < 4; ++i) Ac[i] = An[i];
        }

        int m0 = mt * 128;
        int sec = mt >> 1;                      // 0=Q, 1=K, 2=V
        int hh = ((m0 >> 5) + w) & 7;           // head
        size_t bh = (size_t)(b * 8 + hh) * 32768;
#pragma unroll
        for (int fr = 0; fr < 2; ++fr) {
            int dbase = fr * 16 + g * 4;        // d for r=0..3
            float4 bs = *reinterpret_cast<const float4*>(&bias[m0 + w * 32 + dbase]);
#pragma unroll
            for (int G = 0; G < 2; ++G) {
                int n_g = nt * 32 + G * 16 + q;
                float vm[4];
#pragma unroll
                for (int r = 0; r < 4; ++r) {
                    float a0 = fmaxf(acc[fr][4 * G + 0][r], acc[fr][4 * G + 1][r]);
                    float a1 = fmaxf(acc[fr][4 * G + 2][r], acc[fr][4 * G + 3][r]);
                    vm[r] = fmaxf(a0, a1) + ((const float*)&bs)[r];
                }
                if (sec == 0) {
                    float4 pv = *reinterpret_cast<const float4*>(
                        &pos[(size_t)n_g * 32 + dbase]);
                    u32x2 o2 = {packbf2((vm[0] + pv.x) * QSCALE, (vm[1] + pv.y) * QSCALE),
                                packbf2((vm[2] + pv.z) * QSCALE, (vm[3] + pv.w) * QSCALE)};
                    *reinterpret_cast<u32x2*>(Qb + bh + (size_t)n_g * 32 + dbase) = o2;
                } else if (sec == 1) {
                    u32x2 o2 = {packbf2(vm[0], vm[1]), packbf2(vm[2], vm[3])};
                    *reinterpret_cast<u32x2*>(Kb + bh + (size_t)n_g * 32 + dbase) = o2;
                } else {
#pragma unroll
                    for (int r = 0; r < 4; ++r)
                        Vb[bh + (size_t)(dbase + r) * 1024 + n_g] = (bf16)vm[r];
                }
            }
        }
    }
#undef LOADA
}

// ---------------------------------------------------------------------------
// K5: attention — EXACT r16 production structure (verified ~31us, VGPR 52).
// 4 waves, 64-key tiles, 16 iters (1024 keys), dbuf LDS staging, WAITV(2)
// steady / (0) last, restage gated tt<14.
#define SUBTILE_FULL(K0, K1, V0, V1)                                           \
    {                                                                          \
        f32x16 s = __builtin_amdgcn_mfma_f32_32x32x16_bf16(K0, qf0, zero16(), 0, 0, 0); \
        s = __builtin_amdgcn_mfma_f32_32x32x16_bf16(K1, qf1, s, 0, 0, 0);      \
        float p[16];                                                           \
        _Pragma("unroll")                                                      \
        for (int r = 0; r < 16; ++r) p[r] = EXP2(s[r]);                        \
        float ts = (((p[0]+p[1])+(p[2]+p[3]))+((p[4]+p[5])+(p[6]+p[7]))) +     \
                   (((p[8]+p[9])+(p[10]+p[11]))+((p[12]+p[13])+(p[14]+p[15])));\
        run_s += ts;                                                           \
        u32 pk0 = packbf2(p[0],p[1]),   pk1 = packbf2(p[2],p[3]);              \
        u32 pk2 = packbf2(p[4],p[5]),   pk3 = packbf2(p[6],p[7]);              \
        u32 pk4 = packbf2(p[8],p[9]),   pk5 = packbf2(p[10],p[11]);            \
        u32 pk6 = packbf2(p[12],p[13]), pk7 = packbf2(p[14],p[15]);            \
        i32x2 r02 = pl32swap(pk0, pk2); i32x2 r13 = pl32swap(pk1, pk3);        \
        i32x2 r46 = pl32swap(pk4, pk6); i32x2 r57 = pl32swap(pk5, pk7);        \
        u32x4 b0v = {(u32)r02.x, (u32)r13.x, (u32)r02.y, (u32)r13.y};          \
        u32x4 b1v = {(u32)r46.x, (u32)r57.x, (u32)r46.y, (u32)r57.y};          \
        bf16x8 pb0 = __builtin_bit_cast(bf16x8, b0v);                          \
        bf16x8 pb1 = __builtin_bit_cast(bf16x8, b1v);                          \
        o = __builtin_amdgcn_mfma_f32_32x32x16_bf16(V0, pb0, o, 0, 0, 0);      \
        o = __builtin_amdgcn_mfma_f32_32x32x16_bf16(V1, pb1, o, 0, 0, 0);      \
    }

__global__ __launch_bounds__(256) void k_attn(const bf16* __restrict__ Q,
                                              const bf16* __restrict__ K,
                                              const bf16* __restrict__ V,
                                              float* __restrict__ out) {
    __shared__ __align__(16) bf16 kt[2][2048];
    __shared__ __align__(16) bf16 vt[2][2048];
    int h = blockIdx.x, b = blockIdx.y, qb = blockIdx.z;
    int t = threadIdx.x, w = t >> 6, lane = t & 63;
    int lq = lane & 31, hi = lane >> 5, hi8 = hi * 8;
    size_t bh = (size_t)b * 8 + h;
    const bf16* Qp = Q + bh * 32768;
    const bf16* Kp = K + bh * 32768;
    const bf16* Vp = V + bh * 32768;
    float* Op = out + ((size_t)(b * 256 + h * 32)) * 1024;
    int q0 = qb * 128 + w * 32;

    bf16x8 qf0 = *reinterpret_cast<const bf16x8*>(Qp + (size_t)(q0 + lq) * 32 + hi8);
    bf16x8 qf1 = *reinterpret_cast<const bf16x8*>(Qp + (size_t)(q0 + lq) * 32 + 16 + hi8);

    int srow = lane & 31;
    int sh = w & 1, isV = w >> 1;
    const bf16* sg0;
    if (!isV) sg0 = Kp + (size_t)(sh * 32 + srow) * 32 + (lane >> 5) * 8;
    else      sg0 = Vp + (size_t)srow * 1024 + sh * 32 + (lane >> 5) * 8;
    const bf16* sg1 = sg0 + 16;
    int d0 = sh * 1024, d1 = sh * 1024 + 512;

#define STAGE64(BB, TT)                                                        \
    do {                                                                       \
        if (!isV) {                                                            \
            gload_lds16(sg0 + (size_t)(TT) * 2048, &kt[BB][d0]);               \
            gload_lds16(sg1 + (size_t)(TT) * 2048, &kt[BB][d1]);               \
        } else {                                                               \
            gload_lds16(sg0 + (TT) * 64, &vt[BB][d0]);                         \
            gload_lds16(sg1 + (TT) * 64, &vt[BB][d1]);                         \
        }                                                                      \
    } while (0)

    f32x16 o = zero16();
    float run_s = 0.f;

    STAGE64(0, 0);
    MEMFENCE();
    STAGE64(1, 1);
    MEMFENCE();

    for (int tt = 0; tt < 16; ++tt) {
        int cur = tt & 1;
        if (tt < 15) { WAITV(2); } else { WAITV(0); }
        __builtin_amdgcn_s_barrier();
        __builtin_amdgcn_sched_barrier(0);

        bf16x8 ka0 = *reinterpret_cast<const bf16x8*>(&kt[cur][hi * 256 + lq * 8]);
        bf16x8 ka1 = *reinterpret_cast<const bf16x8*>(&kt[cur][512 + hi * 256 + lq * 8]);
        bf16x8 va0 = *reinterpret_cast<const bf16x8*>(&vt[cur][hi * 256 + lq * 8]);
        bf16x8 va1 = *reinterpret_cast<const bf16x8*>(&vt[cur][512 + hi * 256 + lq * 8]);
        bf16x8 kb0 = *reinterpret_cast<const bf16x8*>(&kt[cur][1024 + hi * 256 + lq * 8]);
        bf16x8 kb1 = *reinterpret_cast<const bf16x8*>(&kt[cur][1536 + hi * 256 + lq * 8]);
        bf16x8 vb0 = *reinterpret_cast<const bf16x8*>(&vt[cur][1024 + hi * 256 + lq * 8]);
        bf16x8 vb1 = *reinterpret_cast<const bf16x8*>(&vt[cur][1536 + hi * 256 + lq * 8]);
        WAITLGKM();
        __builtin_amdgcn_s_barrier();
        __builtin_amdgcn_sched_barrier(0);
        if (tt < 14) STAGE64(cur, tt + 2);
        MEMFENCE();

        SUBTILE_FULL(ka0, ka1, va0, va1);
        SUBTILE_FULL(kb0, kb1, vb0, vb1);
    }
#undef STAGE64

    i32x2 rs = pl32swap(__builtin_bit_cast(u32, run_s), __builtin_bit_cast(u32, run_s));
    float tot = __builtin_bit_cast(float, (u32)rs.x) + __builtin_bit_cast(float, (u32)rs.y);
    float inv = 1.0f / tot;

#pragma unroll
    for (int r = 0; r < 16; ++r) {
        int dd = (r & 3) + 8 * (r >> 2) + 4 * hi;
        Op[(size_t)dd * 1024 + q0 + lq] = o[r] * inv;
    }
}

// ---------------------------------------------------------------------------
extern "C" void kernel_launch(void* const* d_in, const int* in_sizes, int n_in,
                              void* d_out, int out_size, void* d_ws, size_t ws_size,
                              hipStream_t stream) {
    const float* x = (const float*)d_in[0];
    const float* w = (const float*)d_in[1];
    const float* bias = (const float*)d_in[2];
    const float* pos = (const float*)d_in[3];
    float* outp = (float*)d_out;

    char* ws = (char*)d_ws;
    bf16* wb = (bf16*)(ws);               //    393,216
    bf16* Qb = (bf16*)(ws + 393216);      //  8,388,608
    bf16* Kb = (bf16*)(ws + 8781824);     //  8,388,608
    bf16* Vb = (bf16*)(ws + 17170432);    //  8,388,608

    k_convert_w<<<dim3(96), 256, 0, stream>>>(w, wb);
    k_gemm_pool<<<dim3(32, 16), 256, 0, stream>>>(x, wb, bias, pos, Qb, Kb, Vb);
    k_attn<<<dim3(8, 16, 8), 256, 0, stream>>>(Qb, Kb, Vb, outp);
}

// Round 26
// 89.810 us; speedup vs baseline: 1.1604x; 1.0133x over previous
//
#include <hip/hip_runtime.h>
#include <hip/hip_bf16.h>

typedef __bf16 bf16;
typedef bf16 bf16x8 __attribute__((ext_vector_type(8)));
typedef float f32x4 __attribute__((ext_vector_type(4)));
typedef float f32x16 __attribute__((ext_vector_type(16)));
typedef unsigned int u32;
typedef u32 u32x2 __attribute__((ext_vector_type(2)));
typedef u32 u32x4 __attribute__((ext_vector_type(4)));
typedef int i32x2 __attribute__((ext_vector_type(2)));

// Problem constants
// x: [16][256][64][64] f32; w_qkv: [768][256]; b_qkv: [768]; pos: [1024][32]
// out: [16][256][32][32] f32  (= [b][h*32+d][n], n = hp*32+wp)

__device__ __forceinline__ u32 packbf2(float lo, float hi) {
    unsigned short a = __builtin_bit_cast(unsigned short, (bf16)lo);
    unsigned short b = __builtin_bit_cast(unsigned short, (bf16)hi);
    return (u32)a | ((u32)b << 16);
}

#if __has_builtin(__builtin_amdgcn_exp2f)
#define EXP2(x) __builtin_amdgcn_exp2f(x)
#else
#define EXP2(x) __expf((x)*0.69314718055994531f)
#endif

__device__ __forceinline__ i32x2 pl32swap(u32 a, u32 b) {
#if __has_builtin(__builtin_amdgcn_permlane32_swap)
    return __builtin_amdgcn_permlane32_swap((int)a, (int)b, false, false);
#else
    int lid = __builtin_amdgcn_mbcnt_hi(~0u, __builtin_amdgcn_mbcnt_lo(~0u, 0));
    u32 ax = (u32)__shfl_xor((int)a, 32);
    u32 bx = (u32)__shfl_xor((int)b, 32);
    i32x2 r;
    r.x = (int)(lid < 32 ? a : bx);
    r.y = (int)(lid < 32 ? ax : b);
    return r;
#endif
}

__device__ __forceinline__ f32x16 zero16() {
    f32x16 z;
#pragma unroll
    for (int i = 0; i < 16; ++i) z[i] = 0.f;
    return z;
}

// async global->LDS, 16B per lane; ldst must be the wave-uniform base
__device__ __forceinline__ void gload_lds16(const bf16* gsrc, bf16* ldst) {
    __builtin_amdgcn_global_load_lds(
        (const __attribute__((address_space(1))) void*)gsrc,
        (__attribute__((address_space(3))) void*)ldst, 16, 0, 0);
}

// pin memory-op program order at IR level and scheduler level
#define MEMFENCE()                               \
    do {                                         \
        asm volatile("" ::: "memory");           \
        __builtin_amdgcn_sched_barrier(0);       \
    } while (0)

#define WAITV(N)                                                   \
    do {                                                           \
        asm volatile("s_waitcnt vmcnt(" #N ")" ::: "memory");      \
        __builtin_amdgcn_sched_barrier(0);                         \
    } while (0)

#define WAITLGKM()                                                 \
    do {                                                           \
        asm volatile("s_waitcnt lgkmcnt(0)" ::: "memory");         \
        __builtin_amdgcn_sched_barrier(0);                         \
    } while (0)

// ---------------------------------------------------------------------------
// K2: w f32 [768][256] -> bf16 same layout
__global__ __launch_bounds__(256) void k_convert_w(const float* __restrict__ w,
                                                   bf16* __restrict__ wb) {
    int i = (blockIdx.x * 256 + threadIdx.x) * 8;
    float4 a = *reinterpret_cast<const float4*>(w + i);
    float4 b4 = *reinterpret_cast<const float4*>(w + i + 4);
    bf16x8 o;
    o[0] = (bf16)a.x;  o[1] = (bf16)a.y;  o[2] = (bf16)a.z;  o[3] = (bf16)a.w;
    o[4] = (bf16)b4.x; o[5] = (bf16)b4.y; o[6] = (bf16)b4.z; o[7] = (bf16)b4.w;
    *reinterpret_cast<bf16x8*>(wb + i) = o;
}

// ---------------------------------------------------------------------------
// K3: GEMM + pool + fused Q/K/V out, zero-shuffle epilogue + fused-transpose
//     staging — EXACT r22 configuration (best verified: total 90.05us).
//     NEVER hard-cap VGPR via launch_bounds (r18 spill catastrophe).
__global__ __launch_bounds__(256) void k_gemm_pool(const float* __restrict__ x,
                                                   const bf16* __restrict__ wb,
                                                   const float* __restrict__ bias,
                                                   const float* __restrict__ pos,
                                                   bf16* __restrict__ Qb,
                                                   bf16* __restrict__ Kb,
                                                   bf16* __restrict__ Vb) {
    __shared__ __align__(16) bf16 bt[128 * 256];   // 64 KB X-tile [slot][c]
    int b = blockIdx.y, nt = blockIdx.x;
    int t = threadIdx.x;
    int w = t >> 6, lane = t & 63, g = lane >> 4, q = lane & 15;

    const float* xp = x + (size_t)b * 256 * 4096 + nt * 128;  // + c*4096 + j
    const bf16* wb_w = wb + (size_t)(w * 32) * 256;

    // ---- fused transpose staging: c-pairs, packed b32 writes ----
    {
        int j0 = (t & 31) * 4;         // pixel quad within tile
        int cg = (t >> 5) * 2;         // c-pair base 0,2,..,14; pass adds 16
        int sd[4];
        int key[4];
#pragma unroll
        for (int i = 0; i < 4; ++i) {
            int j = j0 + i;
            int s = ((j & 31) >> 1) | ((j & 1) << 4) |
                    (((j >> 5) & 1) << 6) | (((j >> 6) & 1) << 5);
            sd[i] = s * 256;
            key[i] = (s & 7) << 3;
        }
        u32* btw = reinterpret_cast<u32*>(bt);
#pragma unroll
        for (int pass = 0; pass < 16; ++pass) {
            int c = cg + pass * 16;
            float4 v0 = *reinterpret_cast<const float4*>(xp + (size_t)c * 4096 + j0);
            float4 v1 = *reinterpret_cast<const float4*>(xp + (size_t)(c + 1) * 4096 + j0);
            btw[(sd[0] + (c ^ key[0])) >> 1] = packbf2(v0.x, v1.x);
            btw[(sd[1] + (c ^ key[1])) >> 1] = packbf2(v0.y, v1.y);
            btw[(sd[2] + (c ^ key[2])) >> 1] = packbf2(v0.z, v1.z);
            btw[(sd[3] + (c ^ key[3])) >> 1] = packbf2(v0.w, v1.w);
        }
    }

    bf16x8 Ac[4], An[4];
#define LOADA(MT, KC, DST)                                                     \
    {                                                                          \
        _Pragma("unroll")                                                      \
        for (int ks = 0; ks < 2; ++ks)                                         \
            _Pragma("unroll")                                                  \
            for (int fr = 0; fr < 2; ++fr)                                     \
                DST[ks * 2 + fr] = *reinterpret_cast<const bf16x8*>(           \
                    wb_w + (size_t)((MT) * 128 + fr * 16 + q) * 256 +          \
                    (KC) * 64 + ks * 32 + g * 8);                              \
    }
    LOADA(0, 0, Ac);
    MEMFENCE();

    WAITLGKM();
    __builtin_amdgcn_s_barrier();
    __builtin_amdgcn_sched_barrier(0);

    const float QSCALE = 0.2550406682649681f;  // log2(e)/sqrt(32)

    for (int mt = 0; mt < 6; ++mt) {
        f32x4 acc[2][8];
#pragma unroll
        for (int fr = 0; fr < 2; ++fr)
#pragma unroll
            for (int fc = 0; fc < 8; ++fc) acc[fr][fc] = (f32x4){0.f, 0.f, 0.f, 0.f};

#pragma unroll
        for (int kc = 0; kc < 4; ++kc) {
            if (kc < 3) {
                LOADA(mt, kc + 1, An);
            } else if (mt < 5) {
                LOADA(mt + 1, 0, An);
            }
#pragma unroll
            for (int ks = 0; ks < 2; ++ks) {
#pragma unroll
                for (int fc = 0; fc < 8; ++fc) {
                    int co = kc * 64 + (((ks * 4 + g) ^ (q & 7)) << 3);
                    bf16x8 bfv = *reinterpret_cast<const bf16x8*>(
                        &bt[(fc * 16 + q) * 256 + co]);
                    acc[0][fc] = __builtin_amdgcn_mfma_f32_16x16x32_bf16(
                        Ac[ks * 2 + 0], bfv, acc[0][fc], 0, 0, 0);
                    acc[1][fc] = __builtin_amdgcn_mfma_f32_16x16x32_bf16(
                        Ac[ks * 2 + 1], bfv, acc[1][fc], 0, 0, 0);
                }
            }
#pragma unroll
            for (int i = 0; i < 4; ++i) Ac[i] = An[i];
        }

        int m0 = mt * 128;
        int sec = mt >> 1;                      // 0=Q, 1=K, 2=V
        int hh = ((m0 >> 5) + w) & 7;           // head
        size_t bh = (size_t)(b * 8 + hh) * 32768;
#pragma unroll
        for (int fr = 0; fr < 2; ++fr) {
            int dbase = fr * 16 + g * 4;        // d for r=0..3
            float4 bs = *reinterpret_cast<const float4*>(&bias[m0 + w * 32 + dbase]);
#pragma unroll
            for (int G = 0; G < 2; ++G) {
                int n_g = nt * 32 + G * 16 + q;
                float vm[4];
#pragma unroll
                for (int r = 0; r < 4; ++r) {
                    float a0 = fmaxf(acc[fr][4 * G + 0][r], acc[fr][4 * G + 1][r]);
                    float a1 = fmaxf(acc[fr][4 * G + 2][r], acc[fr][4 * G + 3][r]);
                    vm[r] = fmaxf(a0, a1) + ((const float*)&bs)[r];
                }
                if (sec == 0) {
                    float4 pv = *reinterpret_cast<const float4*>(
                        &pos[(size_t)n_g * 32 + dbase]);
                    u32x2 o2 = {packbf2((vm[0] + pv.x) * QSCALE, (vm[1] + pv.y) * QSCALE),
                                packbf2((vm[2] + pv.z) * QSCALE, (vm[3] + pv.w) * QSCALE)};
                    *reinterpret_cast<u32x2*>(Qb + bh + (size_t)n_g * 32 + dbase) = o2;
                } else if (sec == 1) {
                    u32x2 o2 = {packbf2(vm[0], vm[1]), packbf2(vm[2], vm[3])};
                    *reinterpret_cast<u32x2*>(Kb + bh + (size_t)n_g * 32 + dbase) = o2;
                } else {
#pragma unroll
                    for (int r = 0; r < 4; ++r)
                        Vb[bh + (size_t)(dbase + r) * 1024 + n_g] = (bf16)vm[r];
                }
            }
        }
    }
#undef LOADA
}

// ---------------------------------------------------------------------------
// K5: attention — EXACT r16 production structure (verified ~31us, VGPR 52;
// passed full validate+time+revalidate repeatedly). 4 waves, 64-key tiles,
// 16 iters (1024 keys), dbuf LDS staging, WAITV(2) steady / (0) last,
// restage gated tt<14. r25's 2-q-tile variant exposed a replay race and was
// not faster — reverted.
#define SUBTILE_FULL(K0, K1, V0, V1)                                           \
    {                                                                          \
        f32x16 s = __builtin_amdgcn_mfma_f32_32x32x16_bf16(K0, qf0, zero16(), 0, 0, 0); \
        s = __builtin_amdgcn_mfma_f32_32x32x16_bf16(K1, qf1, s, 0, 0, 0);      \
        float p[16];                                                           \
        _Pragma("unroll")                                                      \
        for (int r = 0; r < 16; ++r) p[r] = EXP2(s[r]);                        \
        float ts = (((p[0]+p[1])+(p[2]+p[3]))+((p[4]+p[5])+(p[6]+p[7]))) +     \
                   (((p[8]+p[9])+(p[10]+p[11]))+((p[12]+p[13])+(p[14]+p[15])));\
        run_s += ts;                                                           \
        u32 pk0 = packbf2(p[0],p[1]),   pk1 = packbf2(p[2],p[3]);              \
        u32 pk2 = packbf2(p[4],p[5]),   pk3 = packbf2(p[6],p[7]);              \
        u32 pk4 = packbf2(p[8],p[9]),   pk5 = packbf2(p[10],p[11]);            \
        u32 pk6 = packbf2(p[12],p[13]), pk7 = packbf2(p[14],p[15]);            \
        i32x2 r02 = pl32swap(pk0, pk2); i32x2 r13 = pl32swap(pk1, pk3);        \
        i32x2 r46 = pl32swap(pk4, pk6); i32x2 r57 = pl32swap(pk5, pk7);        \
        u32x4 b0v = {(u32)r02.x, (u32)r13.x, (u32)r02.y, (u32)r13.y};          \
        u32x4 b1v = {(u32)r46.x, (u32)r57.x, (u32)r46.y, (u32)r57.y};          \
        bf16x8 pb0 = __builtin_bit_cast(bf16x8, b0v);                          \
        bf16x8 pb1 = __builtin_bit_cast(bf16x8, b1v);                          \
        o = __builtin_amdgcn_mfma_f32_32x32x16_bf16(V0, pb0, o, 0, 0, 0);      \
        o = __builtin_amdgcn_mfma_f32_32x32x16_bf16(V1, pb1, o, 0, 0, 0);      \
    }

__global__ __launch_bounds__(256) void k_attn(const bf16* __restrict__ Q,
                                              const bf16* __restrict__ K,
                                              const bf16* __restrict__ V,
                                              float* __restrict__ out) {
    __shared__ __align__(16) bf16 kt[2][2048];
    __shared__ __align__(16) bf16 vt[2][2048];
    int h = blockIdx.x, b = blockIdx.y, qb = blockIdx.z;
    int t = threadIdx.x, w = t >> 6, lane = t & 63;
    int lq = lane & 31, hi = lane >> 5, hi8 = hi * 8;
    size_t bh = (size_t)b * 8 + h;
    const bf16* Qp = Q + bh * 32768;
    const bf16* Kp = K + bh * 32768;
    const bf16* Vp = V + bh * 32768;
    float* Op = out + ((size_t)(b * 256 + h * 32)) * 1024;
    int q0 = qb * 128 + w * 32;

    bf16x8 qf0 = *reinterpret_cast<const bf16x8*>(Qp + (size_t)(q0 + lq) * 32 + hi8);
    bf16x8 qf1 = *reinterpret_cast<const bf16x8*>(Qp + (size_t)(q0 + lq) * 32 + 16 + hi8);

    int srow = lane & 31;
    int sh = w & 1, isV = w >> 1;
    const bf16* sg0;
    if (!isV) sg0 = Kp + (size_t)(sh * 32 + srow) * 32 + (lane >> 5) * 8;
    else      sg0 = Vp + (size_t)srow * 1024 + sh * 32 + (lane >> 5) * 8;
    const bf16* sg1 = sg0 + 16;
    int d0 = sh * 1024, d1 = sh * 1024 + 512;

#define STAGE64(BB, TT)                                                        \
    do {                                                                       \
        if (!isV) {                                                            \
            gload_lds16(sg0 + (size_t)(TT) * 2048, &kt[BB][d0]);               \
            gload_lds16(sg1 + (size_t)(TT) * 2048, &kt[BB][d1]);               \
        } else {                                                               \
            gload_lds16(sg0 + (TT) * 64, &vt[BB][d0]);                         \
            gload_lds16(sg1 + (TT) * 64, &vt[BB][d1]);                         \
        }                                                                      \
    } while (0)

    f32x16 o = zero16();
    float run_s = 0.f;

    STAGE64(0, 0);
    MEMFENCE();
    STAGE64(1, 1);
    MEMFENCE();

    for (int tt = 0; tt < 16; ++tt) {
        int cur = tt & 1;
        if (tt < 15) { WAITV(2); } else { WAITV(0); }
        __builtin_amdgcn_s_barrier();
        __builtin_amdgcn_sched_barrier(0);

        bf16x8 ka0 = *reinterpret_cast<const bf16x8*>(&kt[cur][hi * 256 + lq * 8]);
        bf16x8 ka1 = *reinterpret_cast<const bf16x8*>(&kt[cur][512 + hi * 256 + lq * 8]);
        bf16x8 va0 = *reinterpret_cast<const bf16x8*>(&vt[cur][hi * 256 + lq * 8]);
        bf16x8 va1 = *reinterpret_cast<const bf16x8*>(&vt[cur][512 + hi * 256 + lq * 8]);
        bf16x8 kb0 = *reinterpret_cast<const bf16x8*>(&kt[cur][1024 + hi * 256 + lq * 8]);
        bf16x8 kb1 = *reinterpret_cast<const bf16x8*>(&kt[cur][1536 + hi * 256 + lq * 8]);
        bf16x8 vb0 = *reinterpret_cast<const bf16x8*>(&vt[cur][1024 + hi * 256 + lq * 8]);
        bf16x8 vb1 = *reinterpret_cast<const bf16x8*>(&vt[cur][1536 + hi * 256 + lq * 8]);
        WAITLGKM();
        __builtin_amdgcn_s_barrier();
        __builtin_amdgcn_sched_barrier(0);
        if (tt < 14) STAGE64(cur, tt + 2);
        MEMFENCE();

        SUBTILE_FULL(ka0, ka1, va0, va1);
        SUBTILE_FULL(kb0, kb1, vb0, vb1);
    }
#undef STAGE64

    i32x2 rs = pl32swap(__builtin_bit_cast(u32, run_s), __builtin_bit_cast(u32, run_s));
    float tot = __builtin_bit_cast(float, (u32)rs.x) + __builtin_bit_cast(float, (u32)rs.y);
    float inv = 1.0f / tot;

#pragma unroll
    for (int r = 0; r < 16; ++r) {
        int dd = (r & 3) + 8 * (r >> 2) + 4 * hi;
        Op[(size_t)dd * 1024 + q0 + lq] = o[r] * inv;
    }
}

// ---------------------------------------------------------------------------
extern "C" void kernel_launch(void* const* d_in, const int* in_sizes, int n_in,
                              void* d_out, int out_size, void* d_ws, size_t ws_size,
                              hipStream_t stream) {
    const float* x = (const float*)d_in[0];
    const float* w = (const float*)d_in[1];
    const float* bias = (const float*)d_in[2];
    const float* pos = (const float*)d_in[3];
    float* outp = (float*)d_out;

    char* ws = (char*)d_ws;
    bf16* wb = (bf16*)(ws);               //    393,216
    bf16* Qb = (bf16*)(ws + 393216);      //  8,388,608
    bf16* Kb = (bf16*)(ws + 8781824);     //  8,388,608
    bf16* Vb = (bf16*)(ws + 17170432);    //  8,388,608

    k_convert_w<<<dim3(96), 256, 0, stream>>>(w, wb);
    k_gemm_pool<<<dim3(32, 16), 256, 0, stream>>>(x, wb, bias, pos, Qb, Kb, Vb);
    k_attn<<<dim3(8, 16, 8), 256, 0, stream>>>(Qb, Kb, Vb, outp);
}